// Round 1
// baseline (480.433 us; speedup 1.0000x reference)
//
#include <hip/hip_runtime.h>

#define CIN   256
#define COUT  256
#define HH    64
#define WW    64
#define KD    2304         // CIN * 9
#define NPIX  16384        // B * HO * WO

typedef __attribute__((ext_vector_type(8))) short  short8v;
typedef __attribute__((ext_vector_type(4))) float  float4v;
typedef unsigned int u32;
typedef unsigned short u16;

__device__ __forceinline__ u16 f2bf(float f) {
  union { float f; unsigned u; } v; v.f = f;
  unsigned r = v.u + 0x7FFFu + ((v.u >> 16) & 1u);
  return (u16)(r >> 16);
}

__device__ __forceinline__ void gload_lds16(const void* g, void* l) {
  __builtin_amdgcn_global_load_lds((const __attribute__((address_space(1))) u32*)g,
                                   (__attribute__((address_space(3))) u32*)l, 16, 0, 0);
}

// ---------------- Kernel 1: fused sep-conv for offset (18) + mask (9) ----------------
// rec[m][32]: [0..17] = offset (kk*2 + {dy,dx}), [18..26] = 2*sigmoid(mask)
__global__ __launch_bounds__(256) void offmask_kernel(
    const float* __restrict__ x,
    const float* __restrict__ off_dw, const float* __restrict__ off_pw,
    const float* __restrict__ mask_dw, const float* __restrict__ mask_pw,
    float* __restrict__ rec)
{
  int b = blockIdx.z;
  int ty0 = blockIdx.y * 16, tx0 = blockIdx.x * 16;
  int tid = threadIdx.x;
  int ly = tid >> 4, lx = tid & 15;
  int ho = ty0 + ly, wo = tx0 + lx;
  __shared__ float xt[18][18];
  float acc[27];
#pragma unroll
  for (int j = 0; j < 27; ++j) acc[j] = 0.f;
  const float* xb = x + (size_t)b * CIN * 4096;

  for (int c = 0; c < CIN; ++c) {
    __syncthreads();
    for (int i = tid; i < 324; i += 256) {
      int r = i / 18, cc = i - r * 18;
      int gy = ty0 - 1 + r, gx = tx0 - 1 + cc;
      float v = 0.f;
      if (gy >= 0 && gy < HH && gx >= 0 && gx < WW) v = xb[c * 4096 + gy * 64 + gx];
      xt[r][cc] = v;
    }
    __syncthreads();
    float d_off = 0.f, d_msk = 0.f;
#pragma unroll
    for (int t = 0; t < 9; ++t) {
      float xv = xt[ly + (t / 3)][lx + (t % 3)];
      d_off += xv * off_dw[c * 9 + t];
      d_msk += xv * mask_dw[c * 9 + t];
    }
#pragma unroll
    for (int j = 0; j < 18; ++j) acc[j] += d_off * off_pw[j * 256 + c];
#pragma unroll
    for (int j = 0; j < 9; ++j) acc[18 + j] += d_msk * mask_pw[j * 256 + c];
  }
  float* rp = rec + ((size_t)(b * 4096 + ho * 64 + wo)) * 32;
#pragma unroll
  for (int j = 0; j < 18; ++j) rp[j] = acc[j];
#pragma unroll
  for (int j = 0; j < 9; ++j) rp[18 + j] = 2.f / (1.f + __expf(-acc[18 + j]));
}

// ---------------- Kernel 2: weight f32 (co,c,ki,kj) -> bf16 [co][kk*256 + c] ----------------
__global__ __launch_bounds__(256) void wconv_kernel(const float* __restrict__ w,
                                                    u16* __restrict__ wb)
{
  int i = blockIdx.x * 256 + threadIdx.x;     // over COUT*KD
  int co = i / KD, rem = i - co * KD;
  int c = rem / 9, kk = rem - c * 9;
  wb[co * KD + kk * 256 + c] = f2bf(w[i]);
}

// ---------------- Kernel 3: deformable im2col -> col bf16 [m][kk*256 + c] ----------------
__global__ __launch_bounds__(256) void im2col_kernel(
    const float* __restrict__ x, const float* __restrict__ rec,
    u16* __restrict__ col)
{
  int row  = blockIdx.x;           // b*64 + ho
  int cq   = blockIdx.y;           // channel quarter 0..3
  int tid  = threadIdx.x;
  int lane = tid & 63;             // wo
  int w    = tid >> 6;             // 0..3
  int c0   = cq * 64 + w * 16;     // 16 channels per thread
  int b = row >> 6, ho = row & 63;
  int wo = lane;
  int m = row * 64 + wo;
  const float* xb = x + (size_t)b * CIN * 4096;
  const float* rp = rec + (size_t)m * 32;
  u16* cp = col + (size_t)m * KD;

  for (int kk = 0; kk < 9; ++kk) {
    int ki = kk / 3, kj = kk - ki * 3;
    float dy = rp[kk * 2], dx = rp[kk * 2 + 1], msk = rp[18 + kk];
    float py = (float)(ho - 1 + ki) + dy;
    float px = (float)(wo - 1 + kj) + dx;
    float fy = floorf(py), fx = floorf(px);
    int y0 = (int)fy, x0 = (int)fx;
    float wy1 = py - fy, wy0 = 1.f - wy1;
    float wx1 = px - fx, wx0 = 1.f - wx1;
    int idx[4]; float wt[4];
#pragma unroll
    for (int cr = 0; cr < 4; ++cr) {
      int iy = y0 + (cr >> 1), ix = x0 + (cr & 1);
      bool valid = (iy >= 0) & (iy < HH) & (ix >= 0) & (ix < WW);
      int iyc = min(max(iy, 0), HH - 1), ixc = min(max(ix, 0), WW - 1);
      idx[cr] = iyc * 64 + ixc;
      float wy = (cr >> 1) ? wy1 : wy0;
      float wx = (cr & 1) ? wx1 : wx0;
      wt[cr] = valid ? (wy * wx * msk) : 0.f;
    }
    short8v s0, s1;
#pragma unroll
    for (int i = 0; i < 8; ++i) {
      const float* xc = xb + (size_t)(c0 + i) * 4096;
      float s = wt[0] * xc[idx[0]] + wt[1] * xc[idx[1]] +
                wt[2] * xc[idx[2]] + wt[3] * xc[idx[3]];
      s0[i] = (short)f2bf(s);
    }
#pragma unroll
    for (int i = 0; i < 8; ++i) {
      const float* xc = xb + (size_t)(c0 + 8 + i) * 4096;
      float s = wt[0] * xc[idx[0]] + wt[1] * xc[idx[1]] +
                wt[2] * xc[idx[2]] + wt[3] * xc[idx[3]];
      s1[i] = (short)f2bf(s);
    }
    *(short8v*)(cp + kk * 256 + c0)     = s0;
    *(short8v*)(cp + kk * 256 + c0 + 8) = s1;
  }
}

// ---------------- Kernel 4: GEMM  C[co][m] = sum_k wb[co][k] * col[m][k]  (+bias) ----------------
// M=256 (2 tiles) x N=16384 (128 tiles), K=2304 (72 steps of 32). 4 waves, each 64x64.
__global__ __launch_bounds__(256) void gemm_kernel(
    const u16* __restrict__ A,    // wb  [COUT][KD]
    const u16* __restrict__ Bc,   // col [NPIX][KD]
    const float* __restrict__ bias,
    float* __restrict__ out)
{
  __shared__ __align__(16) u16 lA[128 * 32];
  __shared__ __align__(16) u16 lB[128 * 32];
  int tid = threadIdx.x;
  int wave = tid >> 6, lane = tid & 63;
  int i0 = blockIdx.y * 128;   // cout tile
  int n0 = blockIdx.x * 128;   // pixel tile
  int wr = wave >> 1, wc = wave & 1;
  int rl = lane & 15, kq = lane >> 4;

  float4v acc[4][4];
#pragma unroll
  for (int m = 0; m < 4; ++m)
#pragma unroll
    for (int n = 0; n < 4; ++n) acc[m][n] = float4v{0.f, 0.f, 0.f, 0.f};

  for (int ks = 0; ks < 72; ++ks) {
    int k0 = ks * 32;
#pragma unroll
    for (int it = 0; it < 2; ++it) {
      int chunk = it * 4 + wave;             // wave-uniform
      int idx = chunk * 64 + lane;           // 0..511
      int r = idx >> 2, ko = (idx & 3) * 8;
      gload_lds16(A + (size_t)(i0 + r) * KD + k0 + ko, lA + chunk * 512);
      gload_lds16(Bc + (size_t)(n0 + r) * KD + k0 + ko, lB + chunk * 512);
    }
    __syncthreads();
    short8v af[4], bf[4];
#pragma unroll
    for (int m = 0; m < 4; ++m)
      af[m] = *(const short8v*)&lA[(wr * 64 + m * 16 + rl) * 32 + kq * 8];
#pragma unroll
    for (int n = 0; n < 4; ++n)
      bf[n] = *(const short8v*)&lB[(wc * 64 + n * 16 + rl) * 32 + kq * 8];
#pragma unroll
    for (int m = 0; m < 4; ++m)
#pragma unroll
      for (int n = 0; n < 4; ++n)
        acc[m][n] = __builtin_amdgcn_mfma_f32_16x16x32_bf16(af[m], bf[n], acc[m][n], 0, 0, 0);
    __syncthreads();
  }

  int b_img = n0 >> 12;
  int p_base = (n0 & 4095) + wc * 64;
  float* ob = out + (size_t)b_img * COUT * 4096;
#pragma unroll
  for (int m = 0; m < 4; ++m) {
#pragma unroll
    for (int r = 0; r < 4; ++r) {
      int co = i0 + wr * 64 + m * 16 + kq * 4 + r;
      float bv = bias[co];
#pragma unroll
      for (int n = 0; n < 4; ++n) {
        int pp = p_base + n * 16 + rl;
        ob[(size_t)co * 4096 + pp] = acc[m][n][r] + bv;
      }
    }
  }
}

extern "C" void kernel_launch(void* const* d_in, const int* in_sizes, int n_in,
                              void* d_out, int out_size, void* d_ws, size_t ws_size,
                              hipStream_t stream) {
  const float* x       = (const float*)d_in[0];
  const float* weight  = (const float*)d_in[1];
  const float* bias    = (const float*)d_in[2];
  const float* off_dw  = (const float*)d_in[3];
  const float* off_pw  = (const float*)d_in[4];
  const float* mask_dw = (const float*)d_in[5];
  const float* mask_pw = (const float*)d_in[6];

  // ws layout: rec 2,097,152 | wb 1,179,648 | col 75,497,472  => 78,774,272 B
  if (ws_size < 78774272ull) return;
  float* rec = (float*)d_ws;
  u16*   wb  = (u16*)((char*)d_ws + 2097152);
  u16*   col = (u16*)((char*)d_ws + 3276800);
  float* out = (float*)d_out;

  wconv_kernel<<<dim3(2304), dim3(256), 0, stream>>>(weight, wb);
  offmask_kernel<<<dim3(4, 4, 4), dim3(256), 0, stream>>>(x, off_dw, off_pw, mask_dw, mask_pw, rec);
  im2col_kernel<<<dim3(256, 4), dim3(256), 0, stream>>>(x, rec, col);
  gemm_kernel<<<dim3(128, 2), dim3(256), 0, stream>>>(wb, col, bias, out);
}

// Round 2
// 204.872 us; speedup vs baseline: 2.3450x; 2.3450x over previous
//
#include <hip/hip_runtime.h>

#define CIN   256
#define COUT  256
#define HH    64
#define WW    64
#define KD    2304         // CIN * 9
#define NPIX  16384        // B * HO * WO
#define SPLIT 16
#define CPS   (CIN / SPLIT)

typedef __attribute__((ext_vector_type(8))) short  short8v;
typedef __attribute__((ext_vector_type(4))) float  float4v;
typedef unsigned int u32;
typedef unsigned short u16;

__device__ __forceinline__ u16 f2bf(float f) {
  union { float f; unsigned u; } v; v.f = f;
  unsigned r = v.u + 0x7FFFu + ((v.u >> 16) & 1u);
  return (u16)(r >> 16);
}

__device__ __forceinline__ void gload_lds16(const void* g, void* l) {
  __builtin_amdgcn_global_load_lds((const __attribute__((address_space(1))) u32*)g,
                                   (__attribute__((address_space(3))) u32*)l, 16, 0, 0);
}

// ---------------- Kernel 1a: offset/mask partials, channel-split ----------------
// part[s][m][32]: [0..17]=offset partial, [18..26]=mask pre-sigmoid partial
__global__ __launch_bounds__(256) void offmask_part_kernel(
    const float* __restrict__ x,
    const float* __restrict__ off_dw, const float* __restrict__ off_pw,
    const float* __restrict__ mask_dw, const float* __restrict__ mask_pw,
    float* __restrict__ part)
{
  int m = blockIdx.x * 256 + threadIdx.x;   // pixel id: b*4096 + ho*64 + wo
  int s = blockIdx.y;                        // channel split 0..SPLIT-1
  int b = m >> 12, pix = m & 4095;
  int ho = pix >> 6, wo = pix & 63;
  const float* xb = x + (size_t)b * CIN * 4096;

  float acc[27];
#pragma unroll
  for (int j = 0; j < 27; ++j) acc[j] = 0.f;

  int c0 = s * CPS;
  for (int ci = 0; ci < CPS; ++ci) {
    int c = c0 + ci;
    const float* xc = xb + (size_t)c * 4096;
    float d_off = 0.f, d_msk = 0.f;
#pragma unroll
    for (int t = 0; t < 9; ++t) {
      int gy = ho + t / 3 - 1, gx = wo + t % 3 - 1;
      bool ok = (gy >= 0) & (gy < HH) & (gx >= 0) & (gx < WW);
      float v = ok ? xc[gy * 64 + gx] : 0.f;
      d_off += v * off_dw[c * 9 + t];
      d_msk += v * mask_dw[c * 9 + t];
    }
#pragma unroll
    for (int j = 0; j < 18; ++j) acc[j] += d_off * off_pw[j * 256 + c];
#pragma unroll
    for (int j = 0; j < 9; ++j) acc[18 + j] += d_msk * mask_pw[j * 256 + c];
  }
  float* pp = part + ((size_t)s * NPIX + m) * 32;
#pragma unroll
  for (int j = 0; j < 27; ++j) pp[j] = acc[j];
}

// ---------------- Kernel 1b: reduce partials -> rec (sigmoid on mask) ----------------
__global__ __launch_bounds__(256) void offmask_reduce_kernel(
    const float* __restrict__ part, float* __restrict__ rec)
{
  int i = blockIdx.x * 256 + threadIdx.x;   // over NPIX*32
  int m = i >> 5, j = i & 31;
  if (j >= 27) { rec[i] = 0.f; return; }
  float sum = 0.f;
#pragma unroll
  for (int s = 0; s < SPLIT; ++s) sum += part[((size_t)s * NPIX + m) * 32 + j];
  rec[i] = (j < 18) ? sum : 2.f / (1.f + __expf(-sum));
}

// ---------------- Kernel 2: weight f32 (co,c,ki,kj) -> bf16 [co][kk*256 + c] ----------------
__global__ __launch_bounds__(256) void wconv_kernel(const float* __restrict__ w,
                                                    u16* __restrict__ wb)
{
  int i = blockIdx.x * 256 + threadIdx.x;     // over COUT*KD
  int co = i / KD, rem = i - co * KD;
  int c = rem / 9, kk = rem - c * 9;
  wb[co * KD + kk * 256 + c] = f2bf(w[i]);
}

// ---------------- Kernel 3: deformable im2col -> col bf16 [m][kk*256 + c] ----------------
__global__ __launch_bounds__(256) void im2col_kernel(
    const float* __restrict__ x, const float* __restrict__ rec,
    u16* __restrict__ col)
{
  int row  = blockIdx.x;           // b*64 + ho
  int cq   = blockIdx.y;           // channel quarter 0..3
  int tid  = threadIdx.x;
  int lane = tid & 63;             // wo
  int w    = tid >> 6;             // 0..3
  int c0   = cq * 64 + w * 16;     // 16 channels per thread
  int b = row >> 6, ho = row & 63;
  int wo = lane;
  int m = row * 64 + wo;
  const float* xb = x + (size_t)b * CIN * 4096;
  const float* rp = rec + (size_t)m * 32;
  u16* cp = col + (size_t)m * KD;

  for (int kk = 0; kk < 9; ++kk) {
    int ki = kk / 3, kj = kk - ki * 3;
    float dy = rp[kk * 2], dx = rp[kk * 2 + 1], msk = rp[18 + kk];
    float py = (float)(ho - 1 + ki) + dy;
    float px = (float)(wo - 1 + kj) + dx;
    float fy = floorf(py), fx = floorf(px);
    int y0 = (int)fy, x0 = (int)fx;
    float wy1 = py - fy, wy0 = 1.f - wy1;
    float wx1 = px - fx, wx0 = 1.f - wx1;
    int idx[4]; float wt[4];
#pragma unroll
    for (int cr = 0; cr < 4; ++cr) {
      int iy = y0 + (cr >> 1), ix = x0 + (cr & 1);
      bool valid = (iy >= 0) & (iy < HH) & (ix >= 0) & (ix < WW);
      int iyc = min(max(iy, 0), HH - 1), ixc = min(max(ix, 0), WW - 1);
      idx[cr] = iyc * 64 + ixc;
      float wy = (cr >> 1) ? wy1 : wy0;
      float wx = (cr & 1) ? wx1 : wx0;
      wt[cr] = valid ? (wy * wx * msk) : 0.f;
    }
    short8v s0, s1;
#pragma unroll
    for (int i = 0; i < 8; ++i) {
      const float* xc = xb + (size_t)(c0 + i) * 4096;
      float s = wt[0] * xc[idx[0]] + wt[1] * xc[idx[1]] +
                wt[2] * xc[idx[2]] + wt[3] * xc[idx[3]];
      s0[i] = (short)f2bf(s);
    }
#pragma unroll
    for (int i = 0; i < 8; ++i) {
      const float* xc = xb + (size_t)(c0 + 8 + i) * 4096;
      float s = wt[0] * xc[idx[0]] + wt[1] * xc[idx[1]] +
                wt[2] * xc[idx[2]] + wt[3] * xc[idx[3]];
      s1[i] = (short)f2bf(s);
    }
    *(short8v*)(cp + kk * 256 + c0)     = s0;
    *(short8v*)(cp + kk * 256 + c0 + 8) = s1;
  }
}

// ---------------- Kernel 4: GEMM  C[co][m] = sum_k wb[co][k] * col[m][k]  (+bias) ----------------
__global__ __launch_bounds__(256) void gemm_kernel(
    const u16* __restrict__ A,    // wb  [COUT][KD]
    const u16* __restrict__ Bc,   // col [NPIX][KD]
    const float* __restrict__ bias,
    float* __restrict__ out)
{
  __shared__ __align__(16) u16 lA[128 * 32];
  __shared__ __align__(16) u16 lB[128 * 32];
  int tid = threadIdx.x;
  int wave = tid >> 6, lane = tid & 63;
  int i0 = blockIdx.y * 128;   // cout tile
  int n0 = blockIdx.x * 128;   // pixel tile
  int wr = wave >> 1, wc = wave & 1;
  int rl = lane & 15, kq = lane >> 4;

  float4v acc[4][4];
#pragma unroll
  for (int m = 0; m < 4; ++m)
#pragma unroll
    for (int n = 0; n < 4; ++n) acc[m][n] = float4v{0.f, 0.f, 0.f, 0.f};

  for (int ks = 0; ks < 72; ++ks) {
    int k0 = ks * 32;
#pragma unroll
    for (int it = 0; it < 2; ++it) {
      int chunk = it * 4 + wave;             // wave-uniform
      int idx = chunk * 64 + lane;           // 0..511
      int r = idx >> 2, ko = (idx & 3) * 8;
      gload_lds16(A + (size_t)(i0 + r) * KD + k0 + ko, lA + chunk * 512);
      gload_lds16(Bc + (size_t)(n0 + r) * KD + k0 + ko, lB + chunk * 512);
    }
    __syncthreads();
    short8v af[4], bf[4];
#pragma unroll
    for (int m = 0; m < 4; ++m)
      af[m] = *(const short8v*)&lA[(wr * 64 + m * 16 + rl) * 32 + kq * 8];
#pragma unroll
    for (int n = 0; n < 4; ++n)
      bf[n] = *(const short8v*)&lB[(wc * 64 + n * 16 + rl) * 32 + kq * 8];
#pragma unroll
    for (int m = 0; m < 4; ++m)
#pragma unroll
      for (int n = 0; n < 4; ++n)
        acc[m][n] = __builtin_amdgcn_mfma_f32_16x16x32_bf16(af[m], bf[n], acc[m][n], 0, 0, 0);
    __syncthreads();
  }

  int b_img = n0 >> 12;
  int p_base = (n0 & 4095) + wc * 64;
  float* ob = out + (size_t)b_img * COUT * 4096;
#pragma unroll
  for (int m = 0; m < 4; ++m) {
#pragma unroll
    for (int r = 0; r < 4; ++r) {
      int co = i0 + wr * 64 + m * 16 + kq * 4 + r;
      float bv = bias[co];
#pragma unroll
      for (int n = 0; n < 4; ++n) {
        int pp = p_base + n * 16 + rl;
        ob[(size_t)co * 4096 + pp] = acc[m][n][r] + bv;
      }
    }
  }
}

extern "C" void kernel_launch(void* const* d_in, const int* in_sizes, int n_in,
                              void* d_out, int out_size, void* d_ws, size_t ws_size,
                              hipStream_t stream) {
  const float* x       = (const float*)d_in[0];
  const float* weight  = (const float*)d_in[1];
  const float* bias    = (const float*)d_in[2];
  const float* off_dw  = (const float*)d_in[3];
  const float* off_pw  = (const float*)d_in[4];
  const float* mask_dw = (const float*)d_in[5];
  const float* mask_pw = (const float*)d_in[6];

  // ws layout: rec 2,097,152 | wb 1,179,648 | col 75,497,472  => 78,774,272 B
  // offmask partials (16*16384*32*4 = 33.5 MB) ALIAS the col region (written
  // later by im2col, after reduce has consumed the partials).
  if (ws_size < 78774272ull) return;
  float* rec  = (float*)d_ws;
  u16*   wb   = (u16*)((char*)d_ws + 2097152);
  u16*   col  = (u16*)((char*)d_ws + 3276800);
  float* part = (float*)((char*)d_ws + 3276800);
  float* out  = (float*)d_out;

  wconv_kernel<<<dim3(2304), dim3(256), 0, stream>>>(weight, wb);
  offmask_part_kernel<<<dim3(NPIX / 256, SPLIT), dim3(256), 0, stream>>>(
      x, off_dw, off_pw, mask_dw, mask_pw, part);
  offmask_reduce_kernel<<<dim3(NPIX * 32 / 256), dim3(256), 0, stream>>>(part, rec);
  im2col_kernel<<<dim3(256, 4), dim3(256), 0, stream>>>(x, rec, col);
  gemm_kernel<<<dim3(128, 2), dim3(256), 0, stream>>>(wb, col, bias, out);
}

// Round 3
// 128.798 us; speedup vs baseline: 3.7301x; 1.5906x over previous
//
#include <hip/hip_runtime.h>

#define CIN   256
#define COUT  256
#define HH    64
#define WW    64
#define KD    2304         // CIN * 9
#define NPIX  16384        // B * HO * WO
#define SPLIT 16
#define CPS   (CIN / SPLIT)

typedef __attribute__((ext_vector_type(8))) short  short8v;
typedef __attribute__((ext_vector_type(4))) float  float4v;
typedef __attribute__((ext_vector_type(4))) unsigned short ushort4v;
typedef unsigned int u32;
typedef unsigned short u16;

__device__ __forceinline__ u16 f2bf(float f) {
  union { float f; unsigned u; } v; v.f = f;
  unsigned r = v.u + 0x7FFFu + ((v.u >> 16) & 1u);
  return (u16)(r >> 16);
}
__device__ __forceinline__ float bf2f(u16 h) {
  union { unsigned u; float f; } v; v.u = ((unsigned)h) << 16;
  return v.f;
}

__device__ __forceinline__ void gload_lds16(const void* g, void* l) {
  __builtin_amdgcn_global_load_lds((const __attribute__((address_space(1))) u32*)g,
                                   (__attribute__((address_space(3))) u32*)l, 16, 0, 0);
}

// ---------------- Kernel 1a: offset/mask partials, channel-split ----------------
__global__ __launch_bounds__(256) void offmask_part_kernel(
    const float* __restrict__ x,
    const float* __restrict__ off_dw, const float* __restrict__ off_pw,
    const float* __restrict__ mask_dw, const float* __restrict__ mask_pw,
    float* __restrict__ part)
{
  int m = blockIdx.x * 256 + threadIdx.x;   // pixel id: b*4096 + ho*64 + wo
  int s = blockIdx.y;                        // channel split 0..SPLIT-1
  int b = m >> 12, pix = m & 4095;
  int ho = pix >> 6, wo = pix & 63;
  const float* xb = x + (size_t)b * CIN * 4096;

  float acc[27];
#pragma unroll
  for (int j = 0; j < 27; ++j) acc[j] = 0.f;

  int c0 = s * CPS;
  for (int ci = 0; ci < CPS; ++ci) {
    int c = c0 + ci;
    const float* xc = xb + (size_t)c * 4096;
    float d_off = 0.f, d_msk = 0.f;
#pragma unroll
    for (int t = 0; t < 9; ++t) {
      int gy = ho + t / 3 - 1, gx = wo + t % 3 - 1;
      bool ok = (gy >= 0) & (gy < HH) & (gx >= 0) & (gx < WW);
      float v = ok ? xc[gy * 64 + gx] : 0.f;
      d_off += v * off_dw[c * 9 + t];
      d_msk += v * mask_dw[c * 9 + t];
    }
#pragma unroll
    for (int j = 0; j < 18; ++j) acc[j] += d_off * off_pw[j * 256 + c];
#pragma unroll
    for (int j = 0; j < 9; ++j) acc[18 + j] += d_msk * mask_pw[j * 256 + c];
  }
  float* pp = part + ((size_t)s * NPIX + m) * 32;
#pragma unroll
  for (int j = 0; j < 27; ++j) pp[j] = acc[j];
}

// ---------------- Kernel 1b: reduce partials -> rec (sigmoid on mask) ----------------
__global__ __launch_bounds__(256) void offmask_reduce_kernel(
    const float* __restrict__ part, float* __restrict__ rec)
{
  int i = blockIdx.x * 256 + threadIdx.x;   // over NPIX*32
  int m = i >> 5, j = i & 31;
  if (j >= 27) { rec[i] = 0.f; return; }
  float sum = 0.f;
#pragma unroll
  for (int s = 0; s < SPLIT; ++s) sum += part[((size_t)s * NPIX + m) * 32 + j];
  rec[i] = (j < 18) ? sum : 2.f / (1.f + __expf(-sum));
}

// ---------------- Kernel 2: weight f32 (co,c,ki,kj) -> bf16 [co][kk*256 + c] ----------------
__global__ __launch_bounds__(256) void wconv_kernel(const float* __restrict__ w,
                                                    u16* __restrict__ wb)
{
  int i = blockIdx.x * 256 + threadIdx.x;     // over COUT*KD
  int co = i / KD, rem = i - co * KD;
  int c = rem / 9, kk = rem - c * 9;
  wb[co * KD + kk * 256 + c] = f2bf(w[i]);
}

// ---------------- Kernel 2b: x NCHW f32 -> xt NHWC bf16  xt[(b*4096+pix)*256 + c] ----------------
__global__ __launch_bounds__(256) void xpose_kernel(const float* __restrict__ x,
                                                    u16* __restrict__ xt)
{
  __shared__ float t[64][65];
  int ptile = blockIdx.x;   // 64-pixel tile within image (0..63)
  int ctile = blockIdx.y;   // 64-channel tile (0..3)
  int b     = blockIdx.z;
  int tid = threadIdx.x;
  const float* xb = x + (size_t)b * CIN * 4096 + (size_t)ctile * 64 * 4096 + ptile * 64;
#pragma unroll
  for (int i = 0; i < 16; ++i) {
    int c = i * 4 + (tid >> 6), p = tid & 63;
    t[c][p] = xb[(size_t)c * 4096 + p];
  }
  __syncthreads();
  u16* xo = xt + ((size_t)b * 4096 + ptile * 64) * 256 + ctile * 64;
#pragma unroll
  for (int i = 0; i < 16; ++i) {
    int p = i * 4 + (tid >> 6), c = tid & 63;
    xo[(size_t)p * 256 + c] = f2bf(t[c][p]);
  }
}

// ---------------- Kernel 3: deformable im2col from NHWC bf16 ----------------
// wave = 1 pixel at a time; lane covers 4 channels (8B loads, fully coalesced)
__global__ __launch_bounds__(256) void im2col_nhwc_kernel(
    const u16* __restrict__ xt, const float* __restrict__ rec,
    u16* __restrict__ col)
{
  int tid = threadIdx.x;
  int wv = tid >> 6, lane = tid & 63;
  int m0 = blockIdx.x * 16 + wv * 4;

  for (int pi = 0; pi < 4; ++pi) {
    int m = m0 + pi;
    int b = m >> 12, pix = m & 4095;
    int ho = pix >> 6, wo = pix & 63;
    const float* rp = rec + (size_t)m * 32;
    u16* cp = col + (size_t)m * KD;
    const u16* xb = xt + ((size_t)b * 4096) * 256;

#pragma unroll
    for (int kk = 0; kk < 9; ++kk) {
      float dy = rp[kk * 2], dx = rp[kk * 2 + 1], msk = rp[18 + kk];
      float py = (float)(ho - 1 + (kk / 3)) + dy;
      float px = (float)(wo - 1 + (kk % 3)) + dx;
      float fy = floorf(py), fx = floorf(px);
      int y0 = (int)fy, x0 = (int)fx;
      float wy1 = py - fy, wy0 = 1.f - wy1;
      float wx1 = px - fx, wx0 = 1.f - wx1;
      float acc0 = 0.f, acc1 = 0.f, acc2 = 0.f, acc3 = 0.f;
#pragma unroll
      for (int cr = 0; cr < 4; ++cr) {
        int iy = y0 + (cr >> 1), ix = x0 + (cr & 1);
        bool valid = (iy >= 0) & (iy < HH) & (ix >= 0) & (ix < WW);
        int iyc = min(max(iy, 0), HH - 1), ixc = min(max(ix, 0), WW - 1);
        float wy = (cr >> 1) ? wy1 : wy0;
        float wx = (cr & 1) ? wx1 : wx0;
        float wt = valid ? (wy * wx * msk) : 0.f;
        ushort4v v = *(const ushort4v*)(xb + ((size_t)(iyc * 64 + ixc)) * 256 + lane * 4);
        acc0 += wt * bf2f(v[0]);
        acc1 += wt * bf2f(v[1]);
        acc2 += wt * bf2f(v[2]);
        acc3 += wt * bf2f(v[3]);
      }
      ushort4v o;
      o[0] = f2bf(acc0); o[1] = f2bf(acc1); o[2] = f2bf(acc2); o[3] = f2bf(acc3);
      *(ushort4v*)(cp + kk * 256 + lane * 4) = o;
    }
  }
}

// ---------------- Kernel 3-fallback: NCHW im2col (proven R1 path) ----------------
__global__ __launch_bounds__(256) void im2col_kernel(
    const float* __restrict__ x, const float* __restrict__ rec,
    u16* __restrict__ col)
{
  int row  = blockIdx.x;           // b*64 + ho
  int cq   = blockIdx.y;           // channel quarter 0..3
  int tid  = threadIdx.x;
  int lane = tid & 63;             // wo
  int w    = tid >> 6;             // 0..3
  int c0   = cq * 64 + w * 16;     // 16 channels per thread
  int b = row >> 6, ho = row & 63;
  int wo = lane;
  int m = row * 64 + wo;
  const float* xb = x + (size_t)b * CIN * 4096;
  const float* rp = rec + (size_t)m * 32;
  u16* cp = col + (size_t)m * KD;

  for (int kk = 0; kk < 9; ++kk) {
    int ki = kk / 3, kj = kk - ki * 3;
    float dy = rp[kk * 2], dx = rp[kk * 2 + 1], msk = rp[18 + kk];
    float py = (float)(ho - 1 + ki) + dy;
    float px = (float)(wo - 1 + kj) + dx;
    float fy = floorf(py), fx = floorf(px);
    int y0 = (int)fy, x0 = (int)fx;
    float wy1 = py - fy, wy0 = 1.f - wy1;
    float wx1 = px - fx, wx0 = 1.f - wx1;
    int idx[4]; float wt[4];
#pragma unroll
    for (int cr = 0; cr < 4; ++cr) {
      int iy = y0 + (cr >> 1), ix = x0 + (cr & 1);
      bool valid = (iy >= 0) & (iy < HH) & (ix >= 0) & (ix < WW);
      int iyc = min(max(iy, 0), HH - 1), ixc = min(max(ix, 0), WW - 1);
      idx[cr] = iyc * 64 + ixc;
      float wy = (cr >> 1) ? wy1 : wy0;
      float wx = (cr & 1) ? wx1 : wx0;
      wt[cr] = valid ? (wy * wx * msk) : 0.f;
    }
    short8v s0, s1;
#pragma unroll
    for (int i = 0; i < 8; ++i) {
      const float* xc = xb + (size_t)(c0 + i) * 4096;
      float s = wt[0] * xc[idx[0]] + wt[1] * xc[idx[1]] +
                wt[2] * xc[idx[2]] + wt[3] * xc[idx[3]];
      s0[i] = (short)f2bf(s);
    }
#pragma unroll
    for (int i = 0; i < 8; ++i) {
      const float* xc = xb + (size_t)(c0 + 8 + i) * 4096;
      float s = wt[0] * xc[idx[0]] + wt[1] * xc[idx[1]] +
                wt[2] * xc[idx[2]] + wt[3] * xc[idx[3]];
      s1[i] = (short)f2bf(s);
    }
    *(short8v*)(cp + kk * 256 + c0)     = s0;
    *(short8v*)(cp + kk * 256 + c0 + 8) = s1;
  }
}

// ---------------- Kernel 4: GEMM  C[co][m] = sum_k wb[co][k] * col[m][k]  (+bias) ----------------
// XOR-swizzle: logical (row, slot g) lives at physical slot g^(row&3) within the
// 64B LDS row. global_load_lds dest stays linear; the SOURCE address applies the
// inverse (same) permutation; ds_reads apply it on the slot index. 8-way -> 4-way.
__global__ __launch_bounds__(256) void gemm_kernel(
    const u16* __restrict__ A,    // wb  [COUT][KD]
    const u16* __restrict__ Bc,   // col [NPIX][KD]
    const float* __restrict__ bias,
    float* __restrict__ out)
{
  __shared__ __align__(16) u16 lA[128 * 32];
  __shared__ __align__(16) u16 lB[128 * 32];
  int tid = threadIdx.x;
  int wave = tid >> 6, lane = tid & 63;
  int i0 = blockIdx.y * 128;   // cout tile
  int n0 = blockIdx.x * 128;   // pixel tile
  int wr = wave >> 1, wc = wave & 1;
  int rl = lane & 15, kq = lane >> 4;
  int sA = ((kq ^ (rl & 3)) * 8);

  float4v acc[4][4];
#pragma unroll
  for (int m = 0; m < 4; ++m)
#pragma unroll
    for (int n = 0; n < 4; ++n) acc[m][n] = float4v{0.f, 0.f, 0.f, 0.f};

  for (int ks = 0; ks < 72; ++ks) {
    int k0 = ks * 32;
#pragma unroll
    for (int it = 0; it < 2; ++it) {
      int chunk = it * 4 + wave;             // wave-uniform
      int idx = chunk * 64 + lane;           // 0..511
      int r = idx >> 2;
      int ko = ((idx & 3) ^ (r & 3)) * 8;    // swizzled source slot
      gload_lds16(A + (size_t)(i0 + r) * KD + k0 + ko, lA + chunk * 512);
      gload_lds16(Bc + (size_t)(n0 + r) * KD + k0 + ko, lB + chunk * 512);
    }
    __syncthreads();
    short8v af[4], bf[4];
#pragma unroll
    for (int m = 0; m < 4; ++m)
      af[m] = *(const short8v*)&lA[(wr * 64 + m * 16 + rl) * 32 + sA];
#pragma unroll
    for (int n = 0; n < 4; ++n)
      bf[n] = *(const short8v*)&lB[(wc * 64 + n * 16 + rl) * 32 + sA];
#pragma unroll
    for (int m = 0; m < 4; ++m)
#pragma unroll
      for (int n = 0; n < 4; ++n)
        acc[m][n] = __builtin_amdgcn_mfma_f32_16x16x32_bf16(af[m], bf[n], acc[m][n], 0, 0, 0);
    __syncthreads();
  }

  int b_img = n0 >> 12;
  int p_base = (n0 & 4095) + wc * 64;
  float* ob = out + (size_t)b_img * COUT * 4096;
#pragma unroll
  for (int m = 0; m < 4; ++m) {
#pragma unroll
    for (int r = 0; r < 4; ++r) {
      int co = i0 + wr * 64 + m * 16 + kq * 4 + r;
      float bv = bias[co];
#pragma unroll
      for (int n = 0; n < 4; ++n) {
        int pp = p_base + n * 16 + rl;
        ob[(size_t)co * 4096 + pp] = acc[m][n][r] + bv;
      }
    }
  }
}

extern "C" void kernel_launch(void* const* d_in, const int* in_sizes, int n_in,
                              void* d_out, int out_size, void* d_ws, size_t ws_size,
                              hipStream_t stream) {
  const float* x       = (const float*)d_in[0];
  const float* weight  = (const float*)d_in[1];
  const float* bias    = (const float*)d_in[2];
  const float* off_dw  = (const float*)d_in[3];
  const float* off_pw  = (const float*)d_in[4];
  const float* mask_dw = (const float*)d_in[5];
  const float* mask_pw = (const float*)d_in[6];

  // ws layout (NHWC path): rec 2MB | wb 1.18MB | xt 8.39MB | col 75.5MB = 87.2MB
  // part (33.5MB) aliases col (consumed by reduce before im2col writes col).
  float* rec  = (float*)d_ws;
  u16*   wb   = (u16*)((char*)d_ws + 2097152);
  float* out  = (float*)d_out;

  bool nhwc = ws_size >= 87162880ull;
  if (!nhwc && ws_size < 78774272ull) return;

  u16* xt  = (u16*)((char*)d_ws + 3276800);
  u16* col = nhwc ? (u16*)((char*)d_ws + 11665408) : (u16*)((char*)d_ws + 3276800);
  float* part = (float*)col;

  wconv_kernel<<<dim3(2304), dim3(256), 0, stream>>>(weight, wb);
  offmask_part_kernel<<<dim3(NPIX / 256, SPLIT), dim3(256), 0, stream>>>(
      x, off_dw, off_pw, mask_dw, mask_pw, part);
  offmask_reduce_kernel<<<dim3(NPIX * 32 / 256), dim3(256), 0, stream>>>(part, rec);
  if (nhwc) {
    xpose_kernel<<<dim3(64, 4, 4), dim3(256), 0, stream>>>(x, xt);
    im2col_nhwc_kernel<<<dim3(NPIX / 16), dim3(256), 0, stream>>>(xt, rec, col);
  } else {
    im2col_kernel<<<dim3(256, 4), dim3(256), 0, stream>>>(x, rec, col);
  }
  gemm_kernel<<<dim3(128, 2), dim3(256), 0, stream>>>(wb, col, bias, out);
}